// Round 1
// baseline (159.979 us; speedup 1.0000x reference)
//
#include <hip/hip_runtime.h>
#include <hip/hip_bf16.h>

#define B_    512
#define F_    128
#define NTRIP 1024
#define MARGIN 1.0f
#define NBLK  32      // 512/16 blocks per dim of (a,b) space
#define NPB   528     // 32*33/2 upper-triangular blocks

// ws layout (floats)
#define OFF_M    0            // 128*512
#define OFF_G    65536        // 128
#define OFF_TL   65664        // 4 triplet partials (pad to 16)
#define OFF_S    65680        // 128*128
#define OFF_PART 82064        // 528*16384  (~33 MiB total)

// ---------------- triplet loss: one thread per triplet -------------------
__global__ __launch_bounds__(256) void k_triplet(const float* __restrict__ emb,
                                                 const int* __restrict__ trip,
                                                 float* __restrict__ out) {
    int t = blockIdx.x * 256 + threadIdx.x;   // 0..1023
    int a = trip[3 * t]     & (B_ - 1);
    int p = trip[3 * t + 1] & (B_ - 1);
    int n = trip[3 * t + 2] & (B_ - 1);
    const float* ea = emb + a * F_;
    const float* ep = emb + p * F_;
    const float* en = emb + n * F_;
    float ap = 0.f, an = 0.f;
    #pragma unroll 8
    for (int f = 0; f < F_; ++f) {
        float pv = ea[f];
        float d1 = pv - ep[f]; ap = fmaf(d1, d1, ap);
        float d2 = pv - en[f]; an = fmaf(d2, d2, an);
    }
    float l = ap - an + MARGIN;
    l = l > 0.f ? l : 0.f;
    __shared__ float red[256];
    red[threadIdx.x] = l;
    __syncthreads();
    for (int s = 128; s > 0; s >>= 1) {
        if (threadIdx.x < s) red[threadIdx.x] += red[threadIdx.x + s];
        __syncthreads();
    }
    if (threadIdx.x == 0) out[blockIdx.x] = red[0];
}

// ---------------- row means m[i][a] and grand mean g[i] ------------------
__global__ __launch_bounds__(256) void k_m(const float* __restrict__ emb,
                                           float* __restrict__ m,
                                           float* __restrict__ g) {
    int i = blockIdx.x;        // feature
    int t = threadIdx.x;       // 256 threads
    __shared__ float x[B_];
    x[t]       = emb[t * F_ + i];
    x[t + 256] = emb[(t + 256) * F_ + i];
    __syncthreads();
    float xa0 = x[t], xa1 = x[t + 256];
    float s0 = 0.f, s1 = 0.f;
    #pragma unroll 4
    for (int b = 0; b < B_; ++b) {
        float xb = x[b];
        s0 += fabsf(xa0 - xb);
        s1 += fabsf(xa1 - xb);
    }
    m[i * B_ + t]       = s0 * (1.0f / B_);
    m[i * B_ + t + 256] = s1 * (1.0f / B_);
    __shared__ float red[256];
    red[t] = s0 + s1;
    __syncthreads();
    for (int s = 128; s > 0; s >>= 1) {
        if (t < s) red[t] += red[t + s];
        __syncthreads();
    }
    if (t == 0) g[i] = red[0] * (1.0f / ((float)B_ * (float)B_));
}

// ---------------- pair GEMM: T[i,j] = sum_{a<b} d_ab[i]*d_ab[j] ----------
__global__ __launch_bounds__(256) void k_pair(const float* __restrict__ emb,
                                              float* __restrict__ part) {
    const int L = blockIdx.x;           // upper-tri block index
    int ba = 0, rem = L;
    while (rem >= NBLK - ba) { rem -= NBLK - ba; ++ba; }
    const int bb = ba + rem;
    const bool diag = (ba == bb);

    __shared__ __align__(16) float ea[16 * F_];
    __shared__ __align__(16) float eb[16 * F_];
    __shared__ __align__(16) float dl[8 * F_];

    const int t = threadIdx.x;
    // stage the 16 a-rows and 16 b-rows (16 KB)
    {
        const float4* e4  = reinterpret_cast<const float4*>(emb);
        float4* ea4 = reinterpret_cast<float4*>(ea);
        float4* eb4 = reinterpret_cast<float4*>(eb);
        #pragma unroll
        for (int k = 0; k < 2; ++k) {
            int idx = k * 256 + t;               // 0..511 float4s
            ea4[idx] = e4[ba * 512 + idx];
            eb4[idx] = e4[bb * 512 + idx];
        }
    }

    float acc[4][16];
    #pragma unroll
    for (int ii = 0; ii < 4; ++ii)
        #pragma unroll
        for (int jj = 0; jj < 16; ++jj) acc[ii][jj] = 0.f;

    const int f  = t & 127;          // feature for d-compute
    const int pg = t >> 7;           // pair-group 0/1
    const int io = (t & 31) * 4;     // 4-row tile origin
    const int jo = (t >> 5) * 16;    // 16-col tile origin

    __syncthreads();

    for (int bt = 0; bt < 32; ++bt) {
        // compute 8 d-vectors into LDS
        #pragma unroll
        for (int k = 0; k < 4; ++k) {
            int p  = pg * 4 + k;
            int pp = bt * 8 + p;          // 0..255 within block
            int pa = pp >> 4, pb = pp & 15;
            float d = fabsf(ea[pa * F_ + f] - eb[pb * F_ + f]);
            if (diag && pa >= pb) d = 0.f;
            dl[p * F_ + f] = d;
        }
        __syncthreads();
        // rank-1 updates: each thread a 4x16 tile
        #pragma unroll
        for (int p = 0; p < 8; ++p) {
            const float4 di4 = *reinterpret_cast<const float4*>(&dl[p * F_ + io]);
            float di[4] = {di4.x, di4.y, di4.z, di4.w};
            float dj[16];
            #pragma unroll
            for (int q = 0; q < 4; ++q) {
                float4 v = *reinterpret_cast<const float4*>(&dl[p * F_ + jo + 4 * q]);
                dj[4 * q] = v.x; dj[4 * q + 1] = v.y; dj[4 * q + 2] = v.z; dj[4 * q + 3] = v.w;
            }
            #pragma unroll
            for (int ii = 0; ii < 4; ++ii)
                #pragma unroll
                for (int jj = 0; jj < 16; ++jj)
                    acc[ii][jj] = fmaf(di[ii], dj[jj], acc[ii][jj]);
        }
        __syncthreads();
    }

    // write 64 KB partial
    #pragma unroll
    for (int ii = 0; ii < 4; ++ii) {
        #pragma unroll
        for (int q = 0; q < 4; ++q) {
            float4 v = make_float4(acc[ii][4 * q], acc[ii][4 * q + 1],
                                   acc[ii][4 * q + 2], acc[ii][4 * q + 3]);
            *reinterpret_cast<float4*>(
                &part[(size_t)L * 16384 + (size_t)(io + ii) * F_ + jo + 4 * q]) = v;
        }
    }
}

// ---------------- reduce partials + centering corrections ----------------
__global__ __launch_bounds__(256) void k_S(const float* __restrict__ part,
                                           const float* __restrict__ m,
                                           const float* __restrict__ g,
                                           float* __restrict__ S) {
    const int i = blockIdx.x;
    const int t = threadIdx.x;
    const int j = t & 127;
    const int half = t >> 7;            // split work for load ILP

    float T = 0.f;
    const int w0 = half * 264, w1 = w0 + 264;
    for (int w = w0; w < w1; ++w)
        T += part[(size_t)w * 16384 + i * F_ + j];

    float md = 0.f;
    const float* mi = m + i * B_;
    const float* mj = m + j * B_;
    const int a0 = half * 256, a1 = a0 + 256;
    #pragma unroll 4
    for (int a = a0; a < a1; ++a) md = fmaf(mi[a], mj[a], md);

    // linear in the halves: each half carries half of the g term
    float s_local = 2.0f * T * (1.0f / ((float)B_ * (float)B_))
                  - (2.0f / (float)B_) * md
                  + 0.5f * g[i] * g[j];

    __shared__ float red[256];
    red[t] = s_local;
    __syncthreads();
    if (t < 128) S[i * F_ + j] = red[t] + red[t + 128];
}

// ---------------- finalize: corr triu mean + triplet mean ----------------
__global__ __launch_bounds__(256) void k_final(const float* __restrict__ S,
                                               const float* __restrict__ tl,
                                               float* __restrict__ out) {
    const int t = threadIdx.x;
    float sum = 0.f;
    for (int idx = t; idx < F_ * F_; idx += 256) {
        int i = idx >> 7, j = idx & 127;
        if (i < j) {
            float sij = S[idx];
            if (sij < 0.f) sij = 0.f;
            float denom = sqrtf(sqrtf(S[i * F_ + i]) * sqrtf(S[j * F_ + j]));
            sum += sqrtf(sij) / denom;
        }
    }
    __shared__ float red[256];
    red[t] = sum;
    __syncthreads();
    for (int s = 128; s > 0; s >>= 1) {
        if (t < s) red[t] += red[t + s];
        __syncthreads();
    }
    if (t == 0) {
        float corr = red[0] * (1.0f / 8128.0f);   // 128*127/2
        float trip = (tl[0] + tl[1] + tl[2] + tl[3]) * (1.0f / (float)NTRIP);
        out[0] = corr + trip;
    }
}

extern "C" void kernel_launch(void* const* d_in, const int* in_sizes, int n_in,
                              void* d_out, int out_size, void* d_ws, size_t ws_size,
                              hipStream_t stream) {
    const float* emb = (const float*)d_in[0];
    const int*   trp = (const int*)d_in[1];
    float* ws   = (float*)d_ws;
    float* m    = ws + OFF_M;
    float* g    = ws + OFF_G;
    float* tl   = ws + OFF_TL;
    float* S    = ws + OFF_S;
    float* part = ws + OFF_PART;
    float* out  = (float*)d_out;

    k_triplet<<<NTRIP / 256, 256, 0, stream>>>(emb, trp, tl);
    k_m      <<<F_, 256, 0, stream>>>(emb, m, g);
    k_pair   <<<NPB, 256, 0, stream>>>(emb, part);
    k_S      <<<F_, 256, 0, stream>>>(part, m, g, S);
    k_final  <<<1, 256, 0, stream>>>(S, tl, out);
}

// Round 2
// 94.757 us; speedup vs baseline: 1.6883x; 1.6883x over previous
//
#include <hip/hip_runtime.h>
#include <hip/hip_bf16.h>

#define B_    512
#define F_    128
#define NTRIP 1024
#define MARGIN 1.0f
#define NBLK  32      // 512/16 pair-blocks per dim
#define NPB   528     // 32*33/2 upper-tri pair-blocks
#define NGRID 264     // k_pair grid: each block folds 2 pair-blocks

// ws layout (floats)
#define OFF_M    0            // 128*512
#define OFF_G    65536        // 128
#define OFF_TL   65664        // 4 triplet partials (pad to 16)
#define OFF_S    65680        // 128*128
#define OFF_PART 82064        // 264*16384  (~17.6 MB)

typedef __attribute__((ext_vector_type(8))) short bf16x8;
typedef __attribute__((ext_vector_type(4))) float f32x4;

#define LDS_ROW 20   // dwords per Dt row: 32 bf16 = 16 dwords, +4 pad (80 B)

__device__ inline unsigned int bf16r(float f) {   // RNE float->bf16 (f>=0, finite)
    unsigned int u = __float_as_uint(f);
    u += 0x7FFFu + ((u >> 16) & 1u);
    return u >> 16;
}

// ---------------- triplet loss: one thread per triplet -------------------
__global__ __launch_bounds__(256) void k_triplet(const float* __restrict__ emb,
                                                 const int* __restrict__ trip,
                                                 float* __restrict__ out) {
    int t = blockIdx.x * 256 + threadIdx.x;   // 0..1023
    int a = trip[3 * t]     & (B_ - 1);
    int p = trip[3 * t + 1] & (B_ - 1);
    int n = trip[3 * t + 2] & (B_ - 1);
    const float* ea = emb + a * F_;
    const float* ep = emb + p * F_;
    const float* en = emb + n * F_;
    float ap = 0.f, an = 0.f;
    #pragma unroll 8
    for (int f = 0; f < F_; ++f) {
        float pv = ea[f];
        float d1 = pv - ep[f]; ap = fmaf(d1, d1, ap);
        float d2 = pv - en[f]; an = fmaf(d2, d2, an);
    }
    float l = ap - an + MARGIN;
    l = l > 0.f ? l : 0.f;
    __shared__ float red[256];
    red[threadIdx.x] = l;
    __syncthreads();
    for (int s = 128; s > 0; s >>= 1) {
        if (threadIdx.x < s) red[threadIdx.x] += red[threadIdx.x + s];
        __syncthreads();
    }
    if (threadIdx.x == 0) out[blockIdx.x] = red[0];
}

// ---------------- row means m[i][a] and grand mean g[i] ------------------
__global__ __launch_bounds__(256) void k_m(const float* __restrict__ emb,
                                           float* __restrict__ m,
                                           float* __restrict__ g) {
    int i = blockIdx.x;        // feature
    int t = threadIdx.x;       // 256 threads
    __shared__ float x[B_];
    x[t]       = emb[t * F_ + i];
    x[t + 256] = emb[(t + 256) * F_ + i];
    __syncthreads();
    float xa0 = x[t], xa1 = x[t + 256];
    float s0 = 0.f, s1 = 0.f;
    #pragma unroll 4
    for (int b = 0; b < B_; ++b) {
        float xb = x[b];
        s0 += fabsf(xa0 - xb);
        s1 += fabsf(xa1 - xb);
    }
    m[i * B_ + t]       = s0 * (1.0f / B_);
    m[i * B_ + t + 256] = s1 * (1.0f / B_);
    __shared__ float red[256];
    red[t] = s0 + s1;
    __syncthreads();
    for (int s = 128; s > 0; s >>= 1) {
        if (t < s) red[t] += red[t + s];
        __syncthreads();
    }
    if (t == 0) g[i] = red[0] * (1.0f / ((float)B_ * (float)B_));
}

// ---------------- pair GEMM via MFMA: T = D^T D over pair K --------------
// Block: 512 threads (8 waves), folds pair-blocks {bid, bid+264}.
// Per K-step (32 pairs): Dt[128 feat][32 pairs] bf16 in LDS (80B rows),
// wave w computes T rows w*16..+16 x all 128 cols via 8 mfma_16x16x32.
__global__ __launch_bounds__(512) void k_pair(const float* __restrict__ emb,
                                              float* __restrict__ part) {
    __shared__ __align__(16) unsigned int dt[2][F_ * LDS_ROW];   // 2 x 10 KB

    const int t    = threadIdx.x;
    const int lane = t & 63;
    const int w    = t >> 6;          // wave 0..7 -> T row-group
    const int i    = t & 127;         // feature (d-gen)
    const int quarter = t >> 7;       // 0..3: k-range quarter*8..+8
    const int halfq   = quarter >> 1;
    const int pbbase  = (quarter & 1) * 8;

    // fragment address pieces (A and B frags share layout: lane l reads
    // Dt[g*16 + (l&15)][(l>>4)*8 .. +8])
    const int fr_row = lane & 15;
    const int fr_k4  = (lane >> 4) * 4;   // dword offset in row

    f32x4 acc[8];
    #pragma unroll
    for (int c = 0; c < 8; ++c) acc[c] = (f32x4)(0.f);

    for (int half = 0; half < 2; ++half) {
        const int L = blockIdx.x + half * NGRID;   // pair-block id 0..527
        int ba = 0, rem = L;
        while (rem >= NBLK - ba) { rem -= NBLK - ba; ++ba; }
        const int bb = ba + rem;
        const bool diag = (ba == bb);

        // hoist the 8 b-side samples this thread ever needs
        float xb[8];
        #pragma unroll
        for (int kk = 0; kk < 8; ++kk)
            xb[kk] = emb[(bb * 16 + pbbase + kk) * F_ + i];

        for (int s = 0; s < 8; ++s) {
            const int buf = s & 1;
            const int pa  = s * 2 + halfq;          // const per thread per step
            const float xa = emb[(ba * 16 + pa) * F_ + i];
            unsigned int pk[4];
            #pragma unroll
            for (int q = 0; q < 4; ++q) {
                float d0 = fabsf(xa - xb[2 * q]);
                float d1 = fabsf(xa - xb[2 * q + 1]);
                if (diag && pa >= pbbase + 2 * q)     d0 = 0.f;
                if (diag && pa >= pbbase + 2 * q + 1) d1 = 0.f;
                pk[q] = bf16r(d0) | (bf16r(d1) << 16);
            }
            *reinterpret_cast<uint4*>(&dt[buf][i * LDS_ROW + quarter * 4]) =
                make_uint4(pk[0], pk[1], pk[2], pk[3]);
            __syncthreads();

            // A-frag for this wave's row-group (explicit load, no dynamic reg idx)
            const bf16x8 fA = *reinterpret_cast<const bf16x8*>(
                &dt[buf][(w * 16 + fr_row) * LDS_ROW + fr_k4]);
            #pragma unroll
            for (int c = 0; c < 8; ++c) {
                const bf16x8 fB = *reinterpret_cast<const bf16x8*>(
                    &dt[buf][(c * 16 + fr_row) * LDS_ROW + fr_k4]);
                acc[c] = __builtin_amdgcn_mfma_f32_16x16x32_bf16(fA, fB, acc[c], 0, 0, 0);
            }
        }
    }

    // epilogue: C layout col=lane&15, row=(lane>>4)*4+reg
    float* dst = part + (size_t)blockIdx.x * (F_ * F_);
    const int r0 = w * 16 + (lane >> 4) * 4;
    const int cj = lane & 15;
    #pragma unroll
    for (int c = 0; c < 8; ++c)
        #pragma unroll
        for (int r = 0; r < 4; ++r)
            dst[(r0 + r) * F_ + c * 16 + cj] = acc[c][r];
}

// ---------------- reduce partials + centering corrections ----------------
// grid 512: block b -> i = b>>2, j-range (b&3)*32..+32; 8 w-slices of 33
__global__ __launch_bounds__(256) void k_S(const float* __restrict__ part,
                                           const float* __restrict__ m,
                                           const float* __restrict__ g,
                                           float* __restrict__ S) {
    const int i  = blockIdx.x >> 2;
    const int jq = blockIdx.x & 3;
    const int t  = threadIdx.x;
    const int jl = t & 31;
    const int j  = jq * 32 + jl;
    const int sl = t >> 5;             // 0..7

    float T = 0.f;
    for (int wi = sl * 33; wi < sl * 33 + 33; ++wi)
        T += part[(size_t)wi * (F_ * F_) + i * F_ + j];

    float md = 0.f;
    const float* mi = m + i * B_;
    const float* mj = m + j * B_;
    #pragma unroll 4
    for (int a = sl * 64; a < sl * 64 + 64; ++a) md = fmaf(mi[a], mj[a], md);

    float s_local = 2.0f * T * (1.0f / ((float)B_ * (float)B_))
                  - (2.0f / (float)B_) * md
                  + (sl == 0 ? g[i] * g[j] : 0.f);

    __shared__ float red[256];
    red[t] = s_local;
    __syncthreads();
    if (t < 128) red[t] += red[t + 128];
    __syncthreads();
    if (t < 64) red[t] += red[t + 64];
    __syncthreads();
    if (t < 32) S[i * F_ + j] = red[t] + red[t + 32];
}

// ---------------- finalize: corr triu mean + triplet mean ----------------
__global__ __launch_bounds__(256) void k_final(const float* __restrict__ S,
                                               const float* __restrict__ tl,
                                               float* __restrict__ out) {
    const int t = threadIdx.x;
    __shared__ float sq[F_];
    if (t < F_) sq[t] = sqrtf(sqrtf(S[t * F_ + t]));
    __syncthreads();
    float sum = 0.f;
    for (int idx = t; idx < F_ * F_; idx += 256) {
        int i = idx >> 7, j = idx & 127;
        if (i < j) {
            float sij = S[idx];
            if (sij < 0.f) sij = 0.f;
            sum += sqrtf(sij) / (sq[i] * sq[j]);
        }
    }
    __shared__ float red[256];
    red[t] = sum;
    __syncthreads();
    for (int s = 128; s > 0; s >>= 1) {
        if (t < s) red[t] += red[t + s];
        __syncthreads();
    }
    if (t == 0) {
        float corr = red[0] * (1.0f / 8128.0f);   // 128*127/2
        float trip = (tl[0] + tl[1] + tl[2] + tl[3]) * (1.0f / (float)NTRIP);
        out[0] = corr + trip;
    }
}

extern "C" void kernel_launch(void* const* d_in, const int* in_sizes, int n_in,
                              void* d_out, int out_size, void* d_ws, size_t ws_size,
                              hipStream_t stream) {
    const float* emb = (const float*)d_in[0];
    const int*   trp = (const int*)d_in[1];
    float* ws   = (float*)d_ws;
    float* m    = ws + OFF_M;
    float* g    = ws + OFF_G;
    float* tl   = ws + OFF_TL;
    float* S    = ws + OFF_S;
    float* part = ws + OFF_PART;
    float* out  = (float*)d_out;

    k_triplet<<<NTRIP / 256, 256, 0, stream>>>(emb, trp, tl);
    k_m      <<<F_, 256, 0, stream>>>(emb, m, g);
    k_pair   <<<NGRID, 512, 0, stream>>>(emb, part);
    k_S      <<<512, 256, 0, stream>>>(part, m, g, S);
    k_final  <<<1, 256, 0, stream>>>(S, tl, out);
}